// Round 4
// baseline (138217.566 us; speedup 1.0000x reference)
//
#include <hip/hip_runtime.h>
#include <math.h>

#define S_LEN 131072
#define H 100
#define G 400   // 4*H

typedef float v2f __attribute__((ext_vector_type(2)));
typedef float v4f __attribute__((ext_vector_type(4)));

__device__ __forceinline__ float sigmoid_fast(float x) {
    return 1.0f / (1.0f + __expf(-x));
}
__device__ __forceinline__ float tanh_fast(float x) {
    return 2.0f / (1.0f + __expf(-2.0f * x)) - 1.0f;
}

// Round-2 lesson (rule #20): runtime-indexed ext_vector arrays -> scratch.
// Round-3 lesson: even NAMED weight loads got REMATERIALIZED into the loop
// (invariant loads from __restrict__ const arg are "free" to regalloc ->
// VGPR_Count=72, 160KB/step re-streamed from L1/L2, ~1640 cy/step).
// Fix: empty inline-asm pin makes each weight tuple asm-defined -> cannot
// be rematted; allocator must keep it live (256-VGPR budget at 2 waves/EU).
__global__ __launch_bounds__(448, 2) void lstm_seq_kernel(
    const float* __restrict__ x,      // [S]
    const float* __restrict__ W_ih,   // [400]  (400x1)
    const float* __restrict__ W_hh,   // [400,100] row-major
    const float* __restrict__ b_ih,   // [400]
    const float* __restrict__ b_hh,   // [400]
    const float* __restrict__ W_out,  // [100]  (1x100)
    const float* __restrict__ b_out,  // [1]
    float* __restrict__ out)          // [1]
{
    __shared__ __align__(16) float h_lds[112];       // hidden state (100 used)
    __shared__ __align__(16) float act_lds[4][112];  // activated gates i,f,g,o

    const int t = threadIdx.x;
    const bool worker = (t < G);
    const int gidx = t / H;                 // gate block 0..3 (workers only)
    const int rowid = worker ? t : (G - 1); // threads 400-447 shadow row 399
                                            // (loads stay branch-free; stores guarded)

    // ---- 25 NAMED v4f weight registers: W_hh row (100 floats) ----
    v4f w0, w1, w2, w3, w4, w5, w6, w7, w8, w9, w10, w11, w12,
        w13, w14, w15, w16, w17, w18, w19, w20, w21, w22, w23, w24;
    const float* wr = W_hh + rowid * H;     // 400*rowid bytes -> 16B aligned
#define LOADW(i) w##i = *(const v4f*)(wr + 4 * (i))
    LOADW(0);  LOADW(1);  LOADW(2);  LOADW(3);  LOADW(4);
    LOADW(5);  LOADW(6);  LOADW(7);  LOADW(8);  LOADW(9);
    LOADW(10); LOADW(11); LOADW(12); LOADW(13); LOADW(14);
    LOADW(15); LOADW(16); LOADW(17); LOADW(18); LOADW(19);
    LOADW(20); LOADW(21); LOADW(22); LOADW(23); LOADW(24);
#undef LOADW
    // Pin: asm-defined values cannot be rematerialized back into the loop.
    asm volatile("" : "+v"(w0), "+v"(w1), "+v"(w2), "+v"(w3), "+v"(w4),
                      "+v"(w5), "+v"(w6), "+v"(w7), "+v"(w8), "+v"(w9),
                      "+v"(w10), "+v"(w11), "+v"(w12), "+v"(w13), "+v"(w14),
                      "+v"(w15), "+v"(w16), "+v"(w17), "+v"(w18), "+v"(w19),
                      "+v"(w20), "+v"(w21), "+v"(w22), "+v"(w23), "+v"(w24));

    const float wih  = W_ih[rowid];
    const float bsum = b_ih[rowid] + b_hh[rowid];
    float* act_slot = &act_lds[gidx > 3 ? 3 : gidx][rowid - (gidx > 3 ? 3 : gidx) * H];

    float c = 0.0f;                    // cell state, owned by threads 0..99
    if (t < H) h_lds[t] = 0.0f;
    __syncthreads();

    const v4f* hv = (const v4f*)h_lds;

    float xv_next = x[0];              // software-pipelined uniform input load

    for (int step = 0; step < S_LEN; ++step) {
        float xv = xv_next;
        int nxt = (step + 1 < S_LEN) ? (step + 1) : step;
        xv_next = x[nxt];              // issue early; latency hides under matvec

        // ---- matvec: gate = W_hh[row,:] @ h  (4 named v2f chains,
        //      v2f halves to encourage v_pk_fma_f32 formation) ----
        v2f a0 = {0.f, 0.f}, a1 = {0.f, 0.f}, a2 = {0.f, 0.f}, a3 = {0.f, 0.f};
#define FMA4(i, accA, accB)                                                   \
        {   v4f h4 = hv[i];                                                   \
            v2f wlo = {w##i.x, w##i.y}, whi = {w##i.z, w##i.w};               \
            v2f hlo = {h4.x, h4.y},     hhi = {h4.z, h4.w};                   \
            accA = __builtin_elementwise_fma(wlo, hlo, accA);                 \
            accB = __builtin_elementwise_fma(whi, hhi, accB); }
        FMA4(0,  a0, a1); FMA4(1,  a2, a3); FMA4(2,  a0, a1); FMA4(3,  a2, a3);
        FMA4(4,  a0, a1); FMA4(5,  a2, a3); FMA4(6,  a0, a1); FMA4(7,  a2, a3);
        FMA4(8,  a0, a1); FMA4(9,  a2, a3); FMA4(10, a0, a1); FMA4(11, a2, a3);
        FMA4(12, a0, a1); FMA4(13, a2, a3); FMA4(14, a0, a1); FMA4(15, a2, a3);
        FMA4(16, a0, a1); FMA4(17, a2, a3); FMA4(18, a0, a1); FMA4(19, a2, a3);
        FMA4(20, a0, a1); FMA4(21, a2, a3); FMA4(22, a0, a1); FMA4(23, a2, a3);
        FMA4(24, a0, a1);
#undef FMA4
        v2f s = (a0 + a1) + (a2 + a3);
        float gate = (s.x + s.y) + __builtin_fmaf(xv, wih, bsum);
        // activate in the parallel phase (distributes the transcendentals)
        float a = (gidx == 2) ? tanh_fast(gate) : sigmoid_fast(gate);
        if (worker) *act_slot = a;
        __syncthreads();               // gates ready

        if (t < H) {
            float ig = act_lds[0][t];
            float fg = act_lds[1][t];
            float gg = act_lds[2][t];
            float og = act_lds[3][t];
            c = fg * c + ig * gg;
            h_lds[t] = og * tanh_fast(c);
        }
        __syncthreads();               // h ready for next step
    }

    if (t == 0) {
        float s = b_out[0];
        #pragma unroll 4
        for (int j = 0; j < H; ++j) s += W_out[j] * h_lds[j];
        out[0] = s;
    }
}

extern "C" void kernel_launch(void* const* d_in, const int* in_sizes, int n_in,
                              void* d_out, int out_size, void* d_ws, size_t ws_size,
                              hipStream_t stream) {
    const float* x     = (const float*)d_in[0];
    const float* W_ih  = (const float*)d_in[1];
    const float* W_hh  = (const float*)d_in[2];
    const float* b_ih  = (const float*)d_in[3];
    const float* b_hh  = (const float*)d_in[4];
    const float* W_out = (const float*)d_in[5];
    const float* b_out = (const float*)d_in[6];
    float* out = (float*)d_out;

    lstm_seq_kernel<<<1, 448, 0, stream>>>(x, W_ih, W_hh, b_ih, b_hh,
                                           W_out, b_out, out);
}